// Round 7
// baseline (648.235 us; speedup 1.0000x reference)
//
#include <hip/hip_runtime.h>
#include <math.h>

// ============================================================================
// CliffordFourierHead — Cl(3,0) CGENN block. Round 7: ONE persistent kernel
// (256 blocks = 1/CU), hand-rolled device-scope grid barrier between stages
// (kills ~10 x ~9us dispatch overhead), and double-buffered global_load_lds
// GEMM chunks with raw s_waitcnt vmcnt(8)+s_barrier so DMA overlaps MFMA.
// ============================================================================

typedef unsigned short u16;
typedef __attribute__((ext_vector_type(8))) short short8;
typedef __attribute__((ext_vector_type(4))) float f32x4;

#define RSQRT2F 0.70710678118654752440f
#define NBLK 256
#define PS1C (1024 * 256)
#define PS2C (1024 * 512)
#define PSOC (1024 * 128)

__device__ inline void gl_lds16(const void* g, void* l) {
  __builtin_amdgcn_global_load_lds(
      (const __attribute__((address_space(1))) void*)g,
      (__attribute__((address_space(3))) void*)l, 16, 0, 0);
}

// ---- Clifford product tables (verified rounds 0-6) ----
__device__ constexpr int PP_I[64] = {
  0,0,0,0,0,0,0,0,  1,1,1,1,1,1,1,1,  2,2,2,2,2,2,2,2,  3,3,3,3,3,3,3,3,
  4,4,4,4,4,4,4,4,  5,5,5,5,5,5,5,5,  6,6,6,6,6,6,6,6,  7,7,7,7,7,7,7,7};
__device__ constexpr int PP_K[64] = {
  0,1,2,3,4,5,6,7,  0,1,2,3,4,5,6,7,  0,1,2,3,4,5,6,7,  0,1,2,3,4,5,6,7,
  0,1,2,3,4,5,6,7,  0,1,2,3,4,5,6,7,  0,1,2,3,4,5,6,7,  0,1,2,3,4,5,6,7};
__device__ constexpr int PP_C[64] = {
   0, 1, 2, 3, 4, 5, 6, 7,
   9, 8,15,16,13,14,21,20,
  10,15, 8,17,12,21,14,19,
  11,16,17, 8,21,12,13,18,
  29,24,23,35,22,34,33,28,
  30,25,35,23,34,22,32,27,
  31,35,25,24,33,32,22,26,
  43,42,41,40,39,38,37,36};
__device__ constexpr int PP_T[64] = {
   0, 1, 1, 1, 2, 2, 2, 3,
   5, 4, 7, 7, 6, 6, 9, 8,
   5, 7, 4, 7, 6, 9, 6, 8,
   5, 7, 7, 4, 9, 6, 6, 8,
  13,11,11,15,10,14,14,12,
  13,11,15,11,14,10,14,12,
  13,15,11,11,14,14,10,12,
  19,18,18,18,17,17,17,16};
__device__ constexpr int PP_J[64] = {
  0,1,2,3,4,5,6,7,
  1,0,4,5,2,3,7,6,
  2,4,0,6,1,7,3,5,
  3,5,6,0,7,1,2,4,
  4,2,1,7,0,6,5,3,
  5,3,7,1,6,0,4,2,
  6,7,3,2,5,4,0,1,
  7,6,5,4,3,2,1,0};
__device__ constexpr float PP_S[64] = {
  1, 1, 1, 1, 1, 1, 1, 1,
  1, 1, 1, 1, 1, 1, 1, 1,
  1,-1, 1, 1,-1,-1, 1,-1,
  1,-1,-1, 1, 1,-1,-1, 1,
  1,-1, 1, 1,-1,-1, 1,-1,
  1,-1,-1, 1, 1,-1,-1, 1,
  1, 1,-1, 1,-1, 1,-1,-1,
  1, 1,-1, 1,-1, 1,-1,-1};

__device__ constexpr int GJ_CNT[8] = {4,6,6,6,6,6,6,4};
__device__ constexpr int GJ_C[8][6] = {
  {0,8,22,36,0,0},
  {1,9,12,23,26,37},
  {2,10,13,24,27,38},
  {3,11,14,25,28,39},
  {4,15,18,29,32,40},
  {5,16,19,30,33,41},
  {6,17,20,31,34,42},
  {7,21,35,43,0,0}};
__device__ constexpr int GJ_T[8][6] = {
  {0,4,10,16,0,0},
  {1,5,6,11,12,17},
  {1,5,6,11,12,17},
  {1,5,6,11,12,17},
  {2,7,8,13,14,18},
  {2,7,8,13,14,18},
  {2,7,8,13,14,18},
  {3,9,15,19,0,0}};
__device__ constexpr int GRADE[8] = {0,1,1,1,2,2,2,3};

__device__ inline float sigm(float x) { return 1.0f / (1.0f + expf(-x)); }
__device__ inline u16 f2bf(float f) {
  unsigned u = __float_as_uint(f);
  return (u16)((u + 0x7fffu + ((u >> 16) & 1u)) >> 16);
}
__device__ inline float bf2f(u16 h) { return __uint_as_float(((unsigned)h) << 16); }

// ---- device-scope grid barrier (phase-counter, no sense reversal) ----
__device__ void gsync(int* bar, int phase) {
  __syncthreads();
  if (threadIdx.x == 0) {
    __threadfence();  // publish this block's stores (agent scope, L2 wb)
    if (__hip_atomic_fetch_add(&bar[0], 1, __ATOMIC_ACQ_REL,
                               __HIP_MEMORY_SCOPE_AGENT) == NBLK - 1) {
      __hip_atomic_store(&bar[0], 0, __ATOMIC_RELAXED, __HIP_MEMORY_SCOPE_AGENT);
      __hip_atomic_store(&bar[1], phase, __ATOMIC_RELEASE, __HIP_MEMORY_SCOPE_AGENT);
    } else {
      while (__hip_atomic_load(&bar[1], __ATOMIC_ACQUIRE,
                               __HIP_MEMORY_SCOPE_AGENT) < phase)
        __builtin_amdgcn_s_sleep(8);
    }
    __threadfence();  // acquire: invalidate stale lines before reads
  }
  __syncthreads();
}

// ---- kernel argument bundle ----
struct KArgs {
  const float* rin[8]; u16* rout[8]; int rMN[8]; int rS[8];
  const float* x; u16* XB;
  const float *n1_a, *ll1_b, *act_a, *act_b, *ng_a, *llg_b, *wg, *n2_a, *ll2_b;
  u16 *WL1, *WLL1, *WG1, *WLRG, *WLLG, *WLR2, *WLL2, *WG2;
  u16 *HB, *P, *PB16, *hr16, *llg16;
  float* f1;
  float* out;
  int* bar;
};

// ============================================================================
// Stage: weight repacks + x cast (grid-stride)
// ============================================================================
__device__ void repack_stage(const KArgs& a) {
  const int base = blockIdx.x * 256 + threadIdx.x;
  #pragma unroll 1
  for (int sec = 0; sec < 8; ++sec) {
    const float* in = a.rin[sec];
    u16* outp = a.rout[sec];
    const int MN = a.rMN[sec];
    if (a.rS[sec] == 4) {
      for (int mn = base; mn < MN; mn += NBLK * 256) {
        float4 v = ((const float4*)in)[mn];
        outp[(size_t)0 * MN + mn] = f2bf(v.x);
        outp[(size_t)1 * MN + mn] = f2bf(v.y);
        outp[(size_t)2 * MN + mn] = f2bf(v.z);
        outp[(size_t)3 * MN + mn] = f2bf(v.w);
      }
    } else {  // S == 20
      for (int mn = base; mn < MN; mn += NBLK * 256) {
        #pragma unroll
        for (int q = 0; q < 5; ++q) {
          float4 v = *(const float4*)(in + (size_t)mn * 20 + q * 4);
          outp[(size_t)(q * 4 + 0) * MN + mn] = f2bf(v.x);
          outp[(size_t)(q * 4 + 1) * MN + mn] = f2bf(v.y);
          outp[(size_t)(q * 4 + 2) * MN + mn] = f2bf(v.z);
          outp[(size_t)(q * 4 + 3) * MN + mn] = f2bf(v.w);
        }
      }
    }
  }
  for (int mn = base; mn < PS1C; mn += NBLK * 256) {
    float v[8];
    *(float4*)(v)     = *(const float4*)(a.x + (size_t)mn * 8);
    *(float4*)(v + 4) = *(const float4*)(a.x + (size_t)mn * 8 + 4);
    #pragma unroll
    for (int jj = 0; jj < 8; ++jj) a.XB[(size_t)jj * PS1C + mn] = f2bf(v[jj]);
  }
}

// ============================================================================
// Stage: bf16 MFMA GEMM, 128x128 tile, double-buffered LDS DMA pipeline.
// Tile list (set, j, slice, by, mx) walked 256-block grid-stride.
// ============================================================================
__device__ void gemm_stage(
    const u16* __restrict__ Alin, const u16* __restrict__ Pfeat,
    const u16* __restrict__ WLin, const u16* __restrict__ WLin2,
    const u16* __restrict__ WGp,
    void* __restrict__ out1, void* __restrict__ out2,
    int N, int M, int aug, int planeA, int planeO,
    int KSbits, int KCbits, int out16)
{
  __shared__ u16 AsB[2][8192];
  __shared__ u16 BsB[2][8192];

  const int tid  = threadIdx.x;
  const int lane = tid & 63;
  const int wave = tid >> 6;
  const int wr   = wave >> 1;
  const int wc   = wave & 1;
  const int l15  = lane & 15;
  const int lq   = lane >> 4;
  const int srow  = lane >> 3;
  const int sslot = lane & 7;

  const int NMX = M >> 7;
  const int nsets = WLin2 ? 2 : 1;
  const int KS = 1 << KSbits, KC = 1 << KCbits;
  const int ntiles = nsets * 8 * KS * 8 * NMX;

  #pragma unroll 1
  for (int t = blockIdx.x; t < ntiles; t += NBLK) {
    int tmp = t;
    const int mx = tmp % NMX; tmp /= NMX;
    const int by = tmp & 7; tmp >>= 3;
    const int slice = tmp & (KS - 1); tmp >>= KSbits;
    const int j = tmp & 7;
    const int set = tmp >> 3;
    const u16* WL = set ? WLin2 : WLin;
    void* outp = set ? out2 : out1;
    const int b0 = by * 128, m0 = mx * 128;
    const int g = GRADE[j];
    const int npass = aug ? (1 + GJ_CNT[j]) : 1;
    const int cper = (npass << KCbits) >> KSbits;
    const int cbeg = slice * cper;

    f32x4 acc[4][4];
    #pragma unroll
    for (int r = 0; r < 4; ++r)
      #pragma unroll
      for (int c = 0; c < 4; ++c) acc[r][c] = {0.f, 0.f, 0.f, 0.f};

    // prologue DMA for first chunk into buffer 0
    {
      const int ci = cbeg;
      const int p = ci >> KCbits, k0 = (ci & (KC - 1)) << 6;
      const u16* Ab = (p == 0) ? Alin + (size_t)j * planeA
                               : Pfeat + (size_t)GJ_C[j][p - 1] * planeA;
      const u16* Wb = (p == 0) ? WL + (size_t)g * M * N
                               : WGp + (size_t)GJ_T[j][p - 1] * (size_t)M * N;
      const u16* As0 = Ab + (size_t)b0 * N + k0;
      const u16* Bs0 = Wb + (size_t)m0 * N + k0;
      #pragma unroll
      for (int q = 0; q < 4; ++q) {
        int inst = wave * 4 + q, row = inst * 8 + srow;
        int kg = sslot ^ (row & 7);
        gl_lds16(As0 + (size_t)row * N + kg * 8, &AsB[0][inst * 512]);
      }
      #pragma unroll
      for (int q = 0; q < 4; ++q) {
        int inst = wave * 4 + q, row = inst * 8 + srow;
        int kg = sslot ^ (row & 7);
        gl_lds16(Bs0 + (size_t)row * N + kg * 8, &BsB[0][inst * 512]);
      }
    }

    #pragma unroll 1
    for (int ci = cbeg; ci < cbeg + cper; ++ci) {
      const int buf = (ci - cbeg) & 1;
      if (ci + 1 < cbeg + cper) {
        const int cn = ci + 1;
        const int p = cn >> KCbits, k0 = (cn & (KC - 1)) << 6;
        const u16* Ab = (p == 0) ? Alin + (size_t)j * planeA
                                 : Pfeat + (size_t)GJ_C[j][p - 1] * planeA;
        const u16* Wb = (p == 0) ? WL + (size_t)g * M * N
                                 : WGp + (size_t)GJ_T[j][p - 1] * (size_t)M * N;
        const u16* As1 = Ab + (size_t)b0 * N + k0;
        const u16* Bs1 = Wb + (size_t)m0 * N + k0;
        #pragma unroll
        for (int q = 0; q < 4; ++q) {
          int inst = wave * 4 + q, row = inst * 8 + srow;
          int kg = sslot ^ (row & 7);
          gl_lds16(As1 + (size_t)row * N + kg * 8, &AsB[1 - buf][inst * 512]);
        }
        #pragma unroll
        for (int q = 0; q < 4; ++q) {
          int inst = wave * 4 + q, row = inst * 8 + srow;
          int kg = sslot ^ (row & 7);
          gl_lds16(Bs1 + (size_t)row * N + kg * 8, &BsB[1 - buf][inst * 512]);
        }
        // wait only the OLDEST 8 (current chunk's DMAs); prefetch stays in flight
        asm volatile("s_waitcnt vmcnt(8)\n\ts_barrier" ::: "memory");
      } else {
        asm volatile("s_waitcnt vmcnt(0)\n\ts_barrier" ::: "memory");
      }

      const u16* As = &AsB[buf][0];
      const u16* Bs = &BsB[buf][0];
      #pragma unroll
      for (int s = 0; s < 2; ++s) {
        const int kq = s * 4 + lq;
        short8 af[4], bfr[4];
        #pragma unroll
        for (int r = 0; r < 4; ++r) {
          int row = wr * 64 + r * 16 + l15;
          af[r] = *(const short8*)(&As[row * 64 + (kq ^ (row & 7)) * 8]);
        }
        #pragma unroll
        for (int c = 0; c < 4; ++c) {
          int row = wc * 64 + c * 16 + l15;
          bfr[c] = *(const short8*)(&Bs[row * 64 + (kq ^ (row & 7)) * 8]);
        }
        #pragma unroll
        for (int r = 0; r < 4; ++r)
          #pragma unroll
          for (int c = 0; c < 4; ++c)
            acc[r][c] = __builtin_amdgcn_mfma_f32_16x16x32_bf16(af[r], bfr[c], acc[r][c], 0, 0, 0);
      }
      // all waves done reading buf before it becomes next prefetch target
      asm volatile("s_barrier" ::: "memory");
    }

    const size_t po = (size_t)(slice * 8 + j) * planeO;
    #pragma unroll
    for (int r = 0; r < 4; ++r)
      #pragma unroll
      for (int c = 0; c < 4; ++c)
        #pragma unroll
        for (int e = 0; e < 4; ++e) {
          int bb = b0 + wr * 64 + r * 16 + lq * 4 + e;
          int mm = m0 + wc * 64 + c * 16 + l15;
          if (out16) ((u16*)outp)[po + (size_t)bb * M + mm] = f2bf(acc[r][c][e]);
          else       ((float*)outp)[po + (size_t)bb * M + mm] = acc[r][c][e];
        }
  }
}

// ============================================================================
// Elementwise stages (grid-stride)
// ============================================================================
__device__ void pair_norm_stage(const u16* up, const u16* vpart, const float* na,
                                u16* Pp, int PS, int M, int KSl) {
  for (int t = blockIdx.x * 256 + threadIdx.x; t < PS; t += NBLK * 256) {
    int m = t % M;
    float u[8], v[8];
    #pragma unroll
    for (int jj = 0; jj < 8; ++jj) {
      u[jj] = bf2f(up[(size_t)jj * PS + t]);
      float s = 0.f;
      for (int sl = 0; sl < KSl; ++sl) s += bf2f(vpart[(size_t)(sl * 8 + jj) * PS + t]);
      v[jj] = s;
    }
    float q[4];
    q[0] = sqrtf(v[0] * v[0]);
    q[1] = sqrtf(v[1] * v[1] + v[2] * v[2] + v[3] * v[3]);
    q[2] = sqrtf(v[4] * v[4] + v[5] * v[5] + v[6] * v[6]);
    q[3] = sqrtf(v[7] * v[7]);
    float sc[4];
    #pragma unroll
    for (int gg = 0; gg < 4; ++gg) {
      float sa = sigm(na[m * 4 + gg]);
      sc[gg] = 1.0f / (sa * (q[gg] - 1.0f) + 1.0f + 1e-6f);
    }
    #pragma unroll
    for (int jj = 0; jj < 8; ++jj) v[jj] *= sc[GRADE[jj]];
    float p[44];
    #pragma unroll
    for (int c = 0; c < 44; ++c) p[c] = 0.f;
    #pragma unroll
    for (int e = 0; e < 64; ++e)
      p[PP_C[e]] += PP_S[e] * u[PP_I[e]] * v[PP_K[e]];
    #pragma unroll
    for (int c = 0; c < 44; ++c) Pp[(size_t)c * PS + t] = f2bf(p[c]);
  }
}

__device__ void bias_silu_stage(const u16* hpre, const float* bias, const float* ga,
                                const float* gb, u16* sh, int PS, int M) {
  for (int t = blockIdx.x * 256 + threadIdx.x; t < PS; t += NBLK * 256) {
    int m = t % M;
    float v[8];
    #pragma unroll
    for (int jj = 0; jj < 8; ++jj) v[jj] = bf2f(hpre[(size_t)jj * PS + t]);
    v[0] += bias[m];
    #pragma unroll
    for (int jj = 0; jj < 8; ++jj) v[jj] *= RSQRT2F;
    float inv[4];
    inv[0] = v[0];
    inv[1] = v[1]*v[1] + v[2]*v[2] + v[3]*v[3];
    inv[2] = v[4]*v[4] + v[5]*v[5] + v[6]*v[6];
    inv[3] = v[7]*v[7];
    float gt[4];
    #pragma unroll
    for (int gg = 0; gg < 4; ++gg)
      gt[gg] = sigm(ga[m * 4 + gg] * inv[gg] + gb[m * 4 + gg]);
    #pragma unroll
    for (int jj = 0; jj < 8; ++jj)
      sh[(size_t)jj * PS + t] = f2bf(v[jj] * gt[GRADE[jj]]);
  }
}

__device__ void cw_silu_stage(const u16* llg, const u16* up, const u16* hrraw,
                              const float* na, const float* wg, const float* bias,
                              const float* ga, const float* gb, u16* sh, int PS, int M) {
  for (int t = blockIdx.x * 256 + threadIdx.x; t < PS; t += NBLK * 256) {
    int n = t % M;
    float acc[8], u[8], v[8], w[20];
    #pragma unroll
    for (int jj = 0; jj < 8; ++jj) {
      acc[jj] = bf2f(llg[(size_t)jj * PS + t]);
      u[jj]   = bf2f(up[(size_t)jj * PS + t]);
      v[jj]   = bf2f(hrraw[(size_t)jj * PS + t]);
    }
    float q[4];
    q[0] = sqrtf(v[0] * v[0]);
    q[1] = sqrtf(v[1] * v[1] + v[2] * v[2] + v[3] * v[3]);
    q[2] = sqrtf(v[4] * v[4] + v[5] * v[5] + v[6] * v[6]);
    q[3] = sqrtf(v[7] * v[7]);
    float sc[4];
    #pragma unroll
    for (int gg = 0; gg < 4; ++gg) {
      float sa = sigm(na[n * 4 + gg]);
      sc[gg] = 1.0f / (sa * (q[gg] - 1.0f) + 1.0f + 1e-6f);
    }
    #pragma unroll
    for (int jj = 0; jj < 8; ++jj) v[jj] *= sc[GRADE[jj]];
    #pragma unroll
    for (int qq = 0; qq < 5; ++qq)
      *(float4*)(w + qq * 4) = *(const float4*)(wg + (size_t)n * 20 + qq * 4);
    acc[0] += bias[n];
    #pragma unroll
    for (int e = 0; e < 64; ++e)
      acc[PP_J[e]] += PP_S[e] * u[PP_I[e]] * v[PP_K[e]] * w[PP_T[e]];
    #pragma unroll
    for (int jj = 0; jj < 8; ++jj) acc[jj] *= RSQRT2F;
    float inv[4];
    inv[0] = acc[0];
    inv[1] = acc[1]*acc[1] + acc[2]*acc[2] + acc[3]*acc[3];
    inv[2] = acc[4]*acc[4] + acc[5]*acc[5] + acc[6]*acc[6];
    inv[3] = acc[7]*acc[7];
    float gt[4];
    #pragma unroll
    for (int gg = 0; gg < 4; ++gg)
      gt[gg] = sigm(ga[n * 4 + gg] * inv[gg] + gb[n * 4 + gg]);
    #pragma unroll
    for (int jj = 0; jj < 8; ++jj)
      sh[(size_t)jj * PS + t] = f2bf(acc[jj] * gt[GRADE[jj]]);
  }
}

__device__ void final_stage(const float* pre, const float* bias, float* outp,
                            int PS, int M, int KSl) {
  for (int t = blockIdx.x * 256 + threadIdx.x; t < PS; t += NBLK * 256) {
    int m = t % M;
    float v[8];
    #pragma unroll
    for (int jj = 0; jj < 8; ++jj) {
      float s = 0.f;
      for (int sl = 0; sl < KSl; ++sl) s += pre[(size_t)(sl * 8 + jj) * PS + t];
      v[jj] = s;
    }
    v[0] += bias[m];
    #pragma unroll
    for (int jj = 0; jj < 8; ++jj) v[jj] *= RSQRT2F;
    *(float4*)(outp + (size_t)t * 8)     = *(float4*)(v);
    *(float4*)(outp + (size_t)t * 8 + 4) = *(float4*)(v + 4);
  }
}

// ============================================================================
// The persistent mega-kernel
// ============================================================================
__global__ __launch_bounds__(256, 1) void mega(KArgs a) {
  repack_stage(a);
  gsync(a.bar, 1);
  // fcgp1: lr1 GEMM (KS=2, 256 tiles)
  gemm_stage(a.XB, nullptr, a.WL1, nullptr, nullptr, a.PB16, nullptr,
             256, 256, 0, PS1C, PS1C, 1, 2, 1);
  gsync(a.bar, 2);
  pair_norm_stage(a.XB, a.PB16, a.n1_a, a.P, PS1C, 256, 2);
  gsync(a.bar, 3);
  // ll1 + w1 aug GEMM (KS=1, 256 tiles, full-K fp32 accumulate)
  gemm_stage(a.XB, a.P, a.WLL1, nullptr, a.WG1, a.PB16, nullptr,
             256, 512, 1, PS1C, PS2C, 0, 2, 1);
  gsync(a.bar, 4);
  bias_silu_stage(a.PB16, a.ll1_b, a.act_a, a.act_b, a.HB, PS2C, 512);
  gsync(a.bar, 5);
  // lrg + llg fused (2 sets, 512 tiles)
  gemm_stage(a.HB, nullptr, a.WLRG, a.WLLG, nullptr, a.hr16, a.llg16,
             512, 512, 0, PS2C, PS2C, 0, 3, 1);
  gsync(a.bar, 6);
  cw_silu_stage(a.llg16, a.HB, a.hr16, a.ng_a, a.wg, a.llg_b, a.act_a, a.act_b,
                a.HB, PS2C, 512);
  gsync(a.bar, 7);
  // lr2 GEMM (KS=1, 256 tiles)
  gemm_stage(a.HB, nullptr, a.WLR2, nullptr, nullptr, a.PB16, nullptr,
             512, 512, 0, PS2C, PS2C, 0, 3, 1);
  gsync(a.bar, 8);
  pair_norm_stage(a.HB, a.PB16, a.n2_a, a.P, PS2C, 512, 1);
  gsync(a.bar, 9);
  // ll2 + w2 aug GEMM (KS=8, 512 tiles, fp32 partials)
  gemm_stage(a.HB, a.P, a.WLL2, nullptr, a.WG2, a.f1, nullptr,
             512, 128, 1, PS2C, PSOC, 3, 3, 0);
  gsync(a.bar, 10);
  final_stage(a.f1, a.ll2_b, a.out, PSOC, 128, 8);
}

// ============================================================================
extern "C" void kernel_launch(void* const* d_in, const int* in_sizes, int n_in,
                              void* d_out, int out_size, void* d_ws, size_t ws_size,
                              hipStream_t stream)
{
  const float* x     = (const float*)d_in[0];
  const float* lr1_w = (const float*)d_in[1];
  const float* n1_a  = (const float*)d_in[2];
  const float* ll1_w = (const float*)d_in[3];
  const float* ll1_b = (const float*)d_in[4];
  const float* w1    = (const float*)d_in[5];
  const float* act_a = (const float*)d_in[6];
  const float* act_b = (const float*)d_in[7];
  const float* lrg_w = (const float*)d_in[8];
  const float* ng_a  = (const float*)d_in[9];
  const float* llg_w = (const float*)d_in[10];
  const float* llg_b = (const float*)d_in[11];
  const float* wg    = (const float*)d_in[12];
  const float* lr2_w = (const float*)d_in[13];
  const float* n2_a  = (const float*)d_in[14];
  const float* ll2_w = (const float*)d_in[15];
  const float* ll2_b = (const float*)d_in[16];
  const float* w2    = (const float*)d_in[17];

  // ---- workspace carve-up ----
  u16* W = (u16*)d_ws;
  size_t o = 0;
  u16* WL1  = W + o; o +=  262144;   // [4][256*256]
  u16* WLL1 = W + o; o +=  524288;   // [4][512*256]
  u16* WG1  = W + o; o += 2621440;   // [20][512*256]
  u16* WLRG = W + o; o += 1048576;   // [4][512*512]
  u16* WLLG = W + o; o += 1048576;
  u16* WLR2 = W + o; o += 1048576;
  u16* WLL2 = W + o; o +=  262144;   // [4][128*512]
  u16* WG2  = W + o; o += 1310720;   // [20][128*512]
  u16* XB   = W + o; o += 2097152;   // [8][PS1]
  u16* HB   = W + o; o += 4194304;   // [8][PS2]
  u16* P    = W + o; o += 23068672;  // [44][PS2]
  u16* PB16 = W + o; o += 8388608;   // bf16 pre/partial arena (16 MB)
  u16* HRG  = W + o; o += 8388608;   // hr16 + llg16
  u16* hr16  = HRG;
  u16* llg16 = HRG + 4194304;
  float* f1  = (float*)(W + o);      // [64][PSO] fp32 partials, 32 MB
  int* bar   = (int*)(f1 + 8388608); // barrier state (2 ints)
  // total ~140.5 MB < 256 MiB

  KArgs a;
  const float* rins[8] = {lr1_w, ll1_w, w1, lrg_w, llg_w, lr2_w, ll2_w, w2};
  u16* routs[8] = {WL1, WLL1, WG1, WLRG, WLLG, WLR2, WLL2, WG2};
  int rmns[8] = {65536, 131072, 131072, 262144, 262144, 262144, 65536, 65536};
  int rss[8]  = {4, 4, 20, 4, 4, 4, 4, 20};
  for (int i = 0; i < 8; ++i) { a.rin[i] = rins[i]; a.rout[i] = routs[i]; a.rMN[i] = rmns[i]; a.rS[i] = rss[i]; }
  a.x = x; a.XB = XB;
  a.n1_a = n1_a; a.ll1_b = ll1_b; a.act_a = act_a; a.act_b = act_b;
  a.ng_a = ng_a; a.llg_b = llg_b; a.wg = wg; a.n2_a = n2_a; a.ll2_b = ll2_b;
  a.WL1 = WL1; a.WLL1 = WLL1; a.WG1 = WG1; a.WLRG = WLRG; a.WLLG = WLLG;
  a.WLR2 = WLR2; a.WLL2 = WLL2; a.WG2 = WG2;
  a.HB = HB; a.P = P; a.PB16 = PB16; a.hr16 = hr16; a.llg16 = llg16;
  a.f1 = f1; a.out = (float*)d_out; a.bar = bar;

  hipMemsetAsync(bar, 0, 16, stream);
  mega<<<NBLK, 256, 0, stream>>>(a);
}

// Round 8
// 258.334 us; speedup vs baseline: 2.5093x; 2.5093x over previous
//
#include <hip/hip_runtime.h>
#include <math.h>

// ============================================================================
// CliffordFourierHead — Cl(3,0) CGENN block. Round 8: round-5 dispatch
// structure (best known, 261.8us) + double-buffered global_load_lds staging
// in the GEMM: prefetch chunk ci+1 during MFMA of chunk ci, s_waitcnt
// vmcnt(8) so only the current chunk's DMAs are drained at the barrier.
// ============================================================================

typedef unsigned short u16;
typedef __attribute__((ext_vector_type(8))) short short8;
typedef __attribute__((ext_vector_type(4))) float f32x4;

#define RSQRT2F 0.70710678118654752440f

__device__ inline void gl_lds16(const void* g, void* l) {
  __builtin_amdgcn_global_load_lds(
      (const __attribute__((address_space(1))) void*)g,
      (__attribute__((address_space(3))) void*)l, 16, 0, 0);
}

// ---- Clifford product tables (verified rounds 0-7) ----
__device__ constexpr int PP_I[64] = {
  0,0,0,0,0,0,0,0,  1,1,1,1,1,1,1,1,  2,2,2,2,2,2,2,2,  3,3,3,3,3,3,3,3,
  4,4,4,4,4,4,4,4,  5,5,5,5,5,5,5,5,  6,6,6,6,6,6,6,6,  7,7,7,7,7,7,7,7};
__device__ constexpr int PP_K[64] = {
  0,1,2,3,4,5,6,7,  0,1,2,3,4,5,6,7,  0,1,2,3,4,5,6,7,  0,1,2,3,4,5,6,7,
  0,1,2,3,4,5,6,7,  0,1,2,3,4,5,6,7,  0,1,2,3,4,5,6,7,  0,1,2,3,4,5,6,7};
__device__ constexpr int PP_C[64] = {
   0, 1, 2, 3, 4, 5, 6, 7,
   9, 8,15,16,13,14,21,20,
  10,15, 8,17,12,21,14,19,
  11,16,17, 8,21,12,13,18,
  29,24,23,35,22,34,33,28,
  30,25,35,23,34,22,32,27,
  31,35,25,24,33,32,22,26,
  43,42,41,40,39,38,37,36};
__device__ constexpr int PP_T[64] = {
   0, 1, 1, 1, 2, 2, 2, 3,
   5, 4, 7, 7, 6, 6, 9, 8,
   5, 7, 4, 7, 6, 9, 6, 8,
   5, 7, 7, 4, 9, 6, 6, 8,
  13,11,11,15,10,14,14,12,
  13,11,15,11,14,10,14,12,
  13,15,11,11,14,14,10,12,
  19,18,18,18,17,17,17,16};
__device__ constexpr int PP_J[64] = {
  0,1,2,3,4,5,6,7,
  1,0,4,5,2,3,7,6,
  2,4,0,6,1,7,3,5,
  3,5,6,0,7,1,2,4,
  4,2,1,7,0,6,5,3,
  5,3,7,1,6,0,4,2,
  6,7,3,2,5,4,0,1,
  7,6,5,4,3,2,1,0};
__device__ constexpr float PP_S[64] = {
  1, 1, 1, 1, 1, 1, 1, 1,
  1, 1, 1, 1, 1, 1, 1, 1,
  1,-1, 1, 1,-1,-1, 1,-1,
  1,-1,-1, 1, 1,-1,-1, 1,
  1,-1, 1, 1,-1,-1, 1,-1,
  1,-1,-1, 1, 1,-1,-1, 1,
  1, 1,-1, 1,-1, 1,-1,-1,
  1, 1,-1, 1,-1, 1,-1,-1};

__device__ constexpr int GJ_CNT[8] = {4,6,6,6,6,6,6,4};
__device__ constexpr int GJ_C[8][6] = {
  {0,8,22,36,0,0},
  {1,9,12,23,26,37},
  {2,10,13,24,27,38},
  {3,11,14,25,28,39},
  {4,15,18,29,32,40},
  {5,16,19,30,33,41},
  {6,17,20,31,34,42},
  {7,21,35,43,0,0}};
__device__ constexpr int GJ_T[8][6] = {
  {0,4,10,16,0,0},
  {1,5,6,11,12,17},
  {1,5,6,11,12,17},
  {1,5,6,11,12,17},
  {2,7,8,13,14,18},
  {2,7,8,13,14,18},
  {2,7,8,13,14,18},
  {3,9,15,19,0,0}};
__device__ constexpr int GRADE[8] = {0,1,1,1,2,2,2,3};

__device__ inline float sigm(float x) { return 1.0f / (1.0f + expf(-x)); }
__device__ inline u16 f2bf(float f) {
  unsigned u = __float_as_uint(f);
  return (u16)((u + 0x7fffu + ((u >> 16) & 1u)) >> 16);
}
__device__ inline float bf2f(u16 h) { return __uint_as_float(((unsigned)h) << 16); }

// ============================================================================
// bf16 MFMA GEMM, multi-pass + split-K over flattened (pass, k-chunk) list.
// blockIdx.z = (set, j, slice). Slices write disjoint fp32 partial planes
// [slice*8+j][planeO]; consumers sum slices. 128x128 tile, BK=64, 4 waves,
// 4x4 frags of 16x16x32 bf16 MFMA.
// Double-buffered DMA staging: chunk ci+1 prefetched into the other LDS
// buffer while chunk ci is MFMA'd. s_waitcnt vmcnt(8) drains only the
// current chunk's 8 per-wave DMAs; the prefetch's 8 stay in flight.
// XOR bank swizzle folded into the global source address.
// ============================================================================
#define BT 128
#define MT 128
#define BKc 64

__global__ __launch_bounds__(256) void mfma_gemm(
    const u16* __restrict__ Alin, const u16* __restrict__ Pfeat,
    const u16* __restrict__ WLin, const u16* __restrict__ WLin2,
    const u16* __restrict__ WGp,
    float* __restrict__ out1, float* __restrict__ out2,
    int N, int M, int aug, int planeA, int planeO, int KSbits, int KCbits)
{
  const int zz    = blockIdx.z;
  const int set   = zz >> (3 + KSbits);
  const int rem   = zz & ((8 << KSbits) - 1);
  const int j     = rem >> KSbits;
  const int slice = rem & ((1 << KSbits) - 1);
  const u16* WL   = set ? WLin2 : WLin;
  float* outp     = set ? out2 : out1;

  const int b0   = blockIdx.y * BT;
  const int m0   = blockIdx.x * MT;
  const int tid  = threadIdx.x;
  const int lane = tid & 63;
  const int wave = tid >> 6;
  const int wr   = wave >> 1;
  const int wc   = wave & 1;
  const int l15  = lane & 15;
  const int lq   = lane >> 4;

  __shared__ u16 AsB[2][BT * BKc];
  __shared__ u16 BsB[2][MT * BKc];

  f32x4 zero = {0.f, 0.f, 0.f, 0.f};
  f32x4 acc[4][4];
  #pragma unroll
  for (int r = 0; r < 4; ++r)
    #pragma unroll
    for (int c = 0; c < 4; ++c) acc[r][c] = zero;

  const int g = GRADE[j];
  const int npass = aug ? (1 + GJ_CNT[j]) : 1;
  const int KC = 1 << KCbits;
  const int cper = (npass << KCbits) >> KSbits;   // even division by design
  const int cbeg = slice * cper;

  const int srow  = lane >> 3;   // row within instruction
  const int sslot = lane & 7;    // LDS granule slot

  // prologue: DMA first chunk into buffer 0
  {
    const int ci = cbeg;
    const int p  = ci >> KCbits;
    const int k0 = (ci & (KC - 1)) << 6;
    const u16* Ab = (p == 0) ? Alin + (size_t)j * planeA
                             : Pfeat + (size_t)GJ_C[j][p - 1] * planeA;
    const u16* Wb = (p == 0) ? WL + (size_t)g * M * N
                             : WGp + (size_t)GJ_T[j][p - 1] * (size_t)M * N;
    const u16* As0 = Ab + (size_t)b0 * N + k0;
    const u16* Bs0 = Wb + (size_t)m0 * N + k0;
    #pragma unroll
    for (int q = 0; q < 4; ++q) {
      int inst = wave * 4 + q, row = inst * 8 + srow;
      int kg = sslot ^ (row & 7);
      gl_lds16(As0 + (size_t)row * N + kg * 8, &AsB[0][inst * 512]);
    }
    #pragma unroll
    for (int q = 0; q < 4; ++q) {
      int inst = wave * 4 + q, row = inst * 8 + srow;
      int kg = sslot ^ (row & 7);
      gl_lds16(Bs0 + (size_t)row * N + kg * 8, &BsB[0][inst * 512]);
    }
  }

  #pragma unroll 1
  for (int ci = cbeg; ci < cbeg + cper; ++ci) {
    const int buf = (ci - cbeg) & 1;
    if (ci + 1 < cbeg + cper) {
      // prefetch next chunk into the other buffer
      const int cn = ci + 1;
      const int p  = cn >> KCbits;
      const int k0 = (cn & (KC - 1)) << 6;
      const u16* Ab = (p == 0) ? Alin + (size_t)j * planeA
                               : Pfeat + (size_t)GJ_C[j][p - 1] * planeA;
      const u16* Wb = (p == 0) ? WL + (size_t)g * M * N
                               : WGp + (size_t)GJ_T[j][p - 1] * (size_t)M * N;
      const u16* As1 = Ab + (size_t)b0 * N + k0;
      const u16* Bs1 = Wb + (size_t)m0 * N + k0;
      #pragma unroll
      for (int q = 0; q < 4; ++q) {
        int inst = wave * 4 + q, row = inst * 8 + srow;
        int kg = sslot ^ (row & 7);
        gl_lds16(As1 + (size_t)row * N + kg * 8, &AsB[1 - buf][inst * 512]);
      }
      #pragma unroll
      for (int q = 0; q < 4; ++q) {
        int inst = wave * 4 + q, row = inst * 8 + srow;
        int kg = sslot ^ (row & 7);
        gl_lds16(Bs1 + (size_t)row * N + kg * 8, &BsB[1 - buf][inst * 512]);
      }
      // wait only the OLDEST 8 (current chunk's DMAs); prefetch stays in flight
      asm volatile("s_waitcnt vmcnt(8)\n\ts_barrier" ::: "memory");
    } else {
      asm volatile("s_waitcnt vmcnt(0)\n\ts_barrier" ::: "memory");
    }

    const u16* As = &AsB[buf][0];
    const u16* Bs = &BsB[buf][0];
    #pragma unroll
    for (int s = 0; s < 2; ++s) {
      const int kq = s * 4 + lq;
      short8 af[4], bfr[4];
      #pragma unroll
      for (int r = 0; r < 4; ++r) {
        int row = wr * 64 + r * 16 + l15;
        af[r] = *(const short8*)(&As[row * BKc + (kq ^ (row & 7)) * 8]);
      }
      #pragma unroll
      for (int c = 0; c < 4; ++c) {
        int row = wc * 64 + c * 16 + l15;
        bfr[c] = *(const short8*)(&Bs[row * BKc + (kq ^ (row & 7)) * 8]);
      }
      #pragma unroll
      for (int r = 0; r < 4; ++r)
        #pragma unroll
        for (int c = 0; c < 4; ++c)
          acc[r][c] = __builtin_amdgcn_mfma_f32_16x16x32_bf16(af[r], bfr[c], acc[r][c], 0, 0, 0);
    }
    // all waves done reading buf before it becomes the next prefetch target
    asm volatile("s_barrier" ::: "memory");
  }

  float* obase = outp + (size_t)(slice * 8 + j) * planeO;
  #pragma unroll
  for (int r = 0; r < 4; ++r)
    #pragma unroll
    for (int c = 0; c < 4; ++c)
      #pragma unroll
      for (int e = 0; e < 4; ++e) {
        int bb = b0 + wr * 64 + r * 16 + lq * 4 + e;
        int mm = m0 + wc * 64 + c * 16 + l15;
        obase[(size_t)bb * M + mm] = acc[r][c][e];
      }
}

// ============================================================================
// Fused repack (8 weight tensors) + xcast (y==8): fp32 -> bf16 planes
// ============================================================================
struct RepackDesc { const float* in; u16* out; int MN; int S; };
struct RepackArgs { RepackDesc d[8]; const float* x; u16* xp; int PS; };

__global__ void repack_all(RepackArgs a)
{
  int mn = blockIdx.x * 256 + threadIdx.x;
  if (blockIdx.y == 8) {
    if (mn >= a.PS) return;
    float v[8];
    *(float4*)(v)     = *(const float4*)(a.x + (size_t)mn * 8);
    *(float4*)(v + 4) = *(const float4*)(a.x + (size_t)mn * 8 + 4);
    #pragma unroll
    for (int jj = 0; jj < 8; ++jj) a.xp[(size_t)jj * a.PS + mn] = f2bf(v[jj]);
    return;
  }
  RepackDesc d = a.d[blockIdx.y];
  if (mn >= d.MN) return;
  if (d.S == 4) {
    float4 v = ((const float4*)d.in)[mn];
    d.out[(size_t)0 * d.MN + mn] = f2bf(v.x);
    d.out[(size_t)1 * d.MN + mn] = f2bf(v.y);
    d.out[(size_t)2 * d.MN + mn] = f2bf(v.z);
    d.out[(size_t)3 * d.MN + mn] = f2bf(v.w);
  } else {  // S == 20
    #pragma unroll
    for (int q = 0; q < 5; ++q) {
      float4 v = *(const float4*)(d.in + (size_t)mn * 20 + q * 4);
      d.out[(size_t)(q * 4 + 0) * d.MN + mn] = f2bf(v.x);
      d.out[(size_t)(q * 4 + 1) * d.MN + mn] = f2bf(v.y);
      d.out[(size_t)(q * 4 + 2) * d.MN + mn] = f2bf(v.z);
      d.out[(size_t)(q * 4 + 3) * d.MN + mn] = f2bf(v.w);
    }
  }
}

// fused: v = sum_slices(vpart) -> CGENN norm(na) -> pair products with u -> P bf16
__global__ void pair_norm_p(const u16* __restrict__ up, const float* __restrict__ vpart,
                            const float* __restrict__ na, u16* __restrict__ Pp,
                            int PS, int M, int KS)
{
  int t = blockIdx.x * 256 + threadIdx.x;
  if (t >= PS) return;
  int m = t % M;
  float u[8], v[8];
  #pragma unroll
  for (int jj = 0; jj < 8; ++jj) {
    u[jj] = bf2f(up[(size_t)jj * PS + t]);
    float s = 0.f;
    for (int sl = 0; sl < KS; ++sl) s += vpart[(size_t)(sl * 8 + jj) * PS + t];
    v[jj] = s;
  }
  float q[4];
  q[0] = sqrtf(v[0] * v[0]);
  q[1] = sqrtf(v[1] * v[1] + v[2] * v[2] + v[3] * v[3]);
  q[2] = sqrtf(v[4] * v[4] + v[5] * v[5] + v[6] * v[6]);
  q[3] = sqrtf(v[7] * v[7]);
  float sc[4];
  #pragma unroll
  for (int gg = 0; gg < 4; ++gg) {
    float sa = sigm(na[m * 4 + gg]);
    sc[gg] = 1.0f / (sa * (q[gg] - 1.0f) + 1.0f + 1e-6f);
  }
  #pragma unroll
  for (int jj = 0; jj < 8; ++jj) v[jj] *= sc[GRADE[jj]];
  float p[44];
  #pragma unroll
  for (int c = 0; c < 44; ++c) p[c] = 0.f;
  #pragma unroll
  for (int e = 0; e < 64; ++e)
    p[PP_C[e]] += PP_S[e] * u[PP_I[e]] * v[PP_K[e]];
  #pragma unroll
  for (int c = 0; c < 44; ++c) Pp[(size_t)c * PS + t] = f2bf(p[c]);
}

// h = mv_silu((sum_slices + bias0)/sqrt2) -> bf16 planes
__global__ void bias_silu_p(const float* __restrict__ hpart, const float* __restrict__ bias,
                            const float* __restrict__ ga, const float* __restrict__ gb,
                            u16* __restrict__ sh, int PS, int M, int KS)
{
  int t = blockIdx.x * 256 + threadIdx.x;
  if (t >= PS) return;
  int m = t % M;
  float v[8];
  #pragma unroll
  for (int jj = 0; jj < 8; ++jj) {
    float s = 0.f;
    for (int sl = 0; sl < KS; ++sl) s += hpart[(size_t)(sl * 8 + jj) * PS + t];
    v[jj] = s;
  }
  v[0] += bias[m];
  #pragma unroll
  for (int jj = 0; jj < 8; ++jj) v[jj] *= RSQRT2F;
  float inv[4];
  inv[0] = v[0];
  inv[1] = v[1]*v[1] + v[2]*v[2] + v[3]*v[3];
  inv[2] = v[4]*v[4] + v[5]*v[5] + v[6]*v[6];
  inv[3] = v[7]*v[7];
  float gt[4];
  #pragma unroll
  for (int gg = 0; gg < 4; ++gg)
    gt[gg] = sigm(ga[m * 4 + gg] * inv[gg] + gb[m * 4 + gg]);
  #pragma unroll
  for (int jj = 0; jj < 8; ++jj)
    sh[(size_t)jj * PS + t] = f2bf(v[jj] * gt[GRADE[jj]]);
}

// h2 = mv_silu((llg + bias0 + cwGP(u, norm(hr); wg))/sqrt2) -> bf16 planes
__global__ void cw_silu_p(const float* __restrict__ llg, const u16* __restrict__ up,
                          const float* __restrict__ hrraw, const float* __restrict__ na,
                          const float* __restrict__ wg, const float* __restrict__ bias,
                          const float* __restrict__ ga, const float* __restrict__ gb,
                          u16* __restrict__ sh, int PS, int M)
{
  int t = blockIdx.x * 256 + threadIdx.x;
  if (t >= PS) return;
  int n = t % M;
  float acc[8], u[8], v[8], w[20];
  #pragma unroll
  for (int jj = 0; jj < 8; ++jj) {
    acc[jj] = llg[(size_t)jj * PS + t];
    u[jj]   = bf2f(up[(size_t)jj * PS + t]);
    v[jj]   = hrraw[(size_t)jj * PS + t];
  }
  float q[4];
  q[0] = sqrtf(v[0] * v[0]);
  q[1] = sqrtf(v[1] * v[1] + v[2] * v[2] + v[3] * v[3]);
  q[2] = sqrtf(v[4] * v[4] + v[5] * v[5] + v[6] * v[6]);
  q[3] = sqrtf(v[7] * v[7]);
  float sc[4];
  #pragma unroll
  for (int gg = 0; gg < 4; ++gg) {
    float sa = sigm(na[n * 4 + gg]);
    sc[gg] = 1.0f / (sa * (q[gg] - 1.0f) + 1.0f + 1e-6f);
  }
  #pragma unroll
  for (int jj = 0; jj < 8; ++jj) v[jj] *= sc[GRADE[jj]];
  #pragma unroll
  for (int qq = 0; qq < 5; ++qq)
    *(float4*)(w + qq * 4) = *(const float4*)(wg + (size_t)n * 20 + qq * 4);
  acc[0] += bias[n];
  #pragma unroll
  for (int e = 0; e < 64; ++e)
    acc[PP_J[e]] += PP_S[e] * u[PP_I[e]] * v[PP_K[e]] * w[PP_T[e]];
  #pragma unroll
  for (int jj = 0; jj < 8; ++jj) acc[jj] *= RSQRT2F;
  float inv[4];
  inv[0] = acc[0];
  inv[1] = acc[1]*acc[1] + acc[2]*acc[2] + acc[3]*acc[3];
  inv[2] = acc[4]*acc[4] + acc[5]*acc[5] + acc[6]*acc[6];
  inv[3] = acc[7]*acc[7];
  float gt[4];
  #pragma unroll
  for (int gg = 0; gg < 4; ++gg)
    gt[gg] = sigm(ga[n * 4 + gg] * inv[gg] + gb[n * 4 + gg]);
  #pragma unroll
  for (int jj = 0; jj < 8; ++jj)
    sh[(size_t)jj * PS + t] = f2bf(acc[jj] * gt[GRADE[jj]]);
}

// out[b,m,j] = (sum_slices + bias0)/sqrt2, planar -> interleaved
__global__ void final_p(const float* __restrict__ pre, const float* __restrict__ bias,
                        float* __restrict__ outp, int PS, int M, int KS)
{
  int t = blockIdx.x * 256 + threadIdx.x;
  if (t >= PS) return;
  int m = t % M;
  float v[8];
  #pragma unroll
  for (int jj = 0; jj < 8; ++jj) {
    float s = 0.f;
    for (int sl = 0; sl < KS; ++sl) s += pre[(size_t)(sl * 8 + jj) * PS + t];
    v[jj] = s;
  }
  v[0] += bias[m];
  #pragma unroll
  for (int jj = 0; jj < 8; ++jj) v[jj] *= RSQRT2F;
  *(float4*)(outp + (size_t)t * 8)     = *(float4*)(v);
  *(float4*)(outp + (size_t)t * 8 + 4) = *(float4*)(v + 4);
}

// ============================================================================
extern "C" void kernel_launch(void* const* d_in, const int* in_sizes, int n_in,
                              void* d_out, int out_size, void* d_ws, size_t ws_size,
                              hipStream_t stream)
{
  const float* x     = (const float*)d_in[0];
  const float* lr1_w = (const float*)d_in[1];
  const float* n1_a  = (const float*)d_in[2];
  const float* ll1_w = (const float*)d_in[3];
  const float* ll1_b = (const float*)d_in[4];
  const float* w1    = (const float*)d_in[5];
  const float* act_a = (const float*)d_in[6];
  const float* act_b = (const float*)d_in[7];
  const float* lrg_w = (const float*)d_in[8];
  const float* ng_a  = (const float*)d_in[9];
  const float* llg_w = (const float*)d_in[10];
  const float* llg_b = (const float*)d_in[11];
  const float* wg    = (const float*)d_in[12];
  const float* lr2_w = (const float*)d_in[13];
  const float* n2_a  = (const float*)d_in[14];
  const float* ll2_w = (const float*)d_in[15];
  const float* ll2_b = (const float*)d_in[16];
  const float* w2    = (const float*)d_in[17];
  float* out = (float*)d_out;

  // ---- workspace carve-up ----
  u16* W = (u16*)d_ws;
  size_t o = 0;
  u16* WL1  = W + o; o +=  262144;   // [4][256*256]
  u16* WLL1 = W + o; o +=  524288;   // [4][512*256]
  u16* WG1  = W + o; o += 2621440;   // [20][512*256]
  u16* WLRG = W + o; o += 1048576;   // [4][512*512]
  u16* WLLG = W + o; o += 1048576;
  u16* WLR2 = W + o; o += 1048576;
  u16* WLL2 = W + o; o +=  262144;   // [4][128*512]
  u16* WG2  = W + o; o += 1310720;   // [20][128*512]
  u16* XB   = W + o; o += 2097152;   // [8][1024*256]
  u16* HB   = W + o; o += 4194304;   // [8][1024*512] (h1 bf16, then h2 bf16)
  u16* P    = W + o; o += 23068672;  // [44][1024*512]
  float* f1 = (float*)(W + o);       // 8,388,608 f: lr1/ll1/lr2 KS2 partials, ll2 KS8 partials
  float* f2 = f1 + 8388608;          // 8,388,608 f: hr(16MB)+llg(16MB), KS=1
  float* hrP  = f2;
  float* llgP = f2 + 4194304;

  dim3 blk(256);
  const int PS1 = 1024 * 256, PS2 = 1024 * 512, PSO = 1024 * 128;

  // ---- fused repacks + xcast ----
  RepackArgs ra = {{
    {lr1_w, WL1, 65536, 4}, {ll1_w, WLL1, 131072, 4}, {w1, WG1, 131072, 20},
    {lrg_w, WLRG, 262144, 4}, {llg_w, WLLG, 262144, 4}, {lr2_w, WLR2, 262144, 4},
    {ll2_w, WLL2, 65536, 4}, {w2, WG2, 65536, 20}},
    x, XB, PS1};
  repack_all<<<dim3(1024, 9), blk, 0, stream>>>(ra);

  // ---- fcgp1 (N=256, M=512) ----
  // lr1: KS=2 -> 256 blocks
  mfma_gemm<<<dim3(2, 8, 16), blk, 0, stream>>>(XB, nullptr, WL1, nullptr, nullptr,
      f1, nullptr, 256, 256, 0, PS1, PS1, 1, 2);
  pair_norm_p<<<PS1 / 256, blk, 0, stream>>>(XB, f1, n1_a, P, PS1, 256, 2);
  // ll1 + w1 aug: KS=2 -> 512 blocks
  mfma_gemm<<<dim3(4, 8, 16), blk, 0, stream>>>(XB, P, WLL1, nullptr, WG1,
      f1, nullptr, 256, 512, 1, PS1, PS2, 1, 2);
  bias_silu_p<<<PS2 / 256, blk, 0, stream>>>(f1, ll1_b, act_a, act_b, HB, PS2, 512, 2);

  // ---- channel-wise GP layer: lrg + llg fused, KS=1 -> 512 blocks ----
  mfma_gemm<<<dim3(4, 8, 16), blk, 0, stream>>>(HB, nullptr, WLRG, WLLG, nullptr,
      hrP, llgP, 512, 512, 0, PS2, PS2, 0, 3);
  cw_silu_p<<<PS2 / 256, blk, 0, stream>>>(llgP, HB, hrP, ng_a, wg, llg_b, act_a, act_b,
      HB, PS2, 512);

  // ---- fcgp2 (N=512, M=128) ----
  // lr2: KS=2 -> 512 blocks
  mfma_gemm<<<dim3(4, 8, 16), blk, 0, stream>>>(HB, nullptr, WLR2, nullptr, nullptr,
      f1, nullptr, 512, 512, 0, PS2, PS2, 1, 3);
  pair_norm_p<<<PS2 / 256, blk, 0, stream>>>(HB, f1, n2_a, P, PS2, 512, 2);
  // ll2 + w2 aug: KS=8 -> 512 blocks
  mfma_gemm<<<dim3(1, 8, 64), blk, 0, stream>>>(HB, P, WLL2, nullptr, WG2,
      f1, nullptr, 512, 128, 1, PS2, PSO, 3, 3);
  final_p<<<PSO / 256, blk, 0, stream>>>(f1, ll2_b, out, PSO, 128, 8);
}

// Round 9
// 252.990 us; speedup vs baseline: 2.5623x; 1.0211x over previous
//
#include <hip/hip_runtime.h>
#include <math.h>

// ============================================================================
// CliffordFourierHead — Cl(3,0) CGENN block. Round 9: round-8 structure
// (best known, 258.3us: split-K dispatch GEMMs + double-buffered
// global_load_lds) with bf16 intermediate planes everywhere except the
// final GEMM's fp32 split-K partials (KS 8->4). ~144MB less traffic.
// ============================================================================

typedef unsigned short u16;
typedef __attribute__((ext_vector_type(8))) short short8;
typedef __attribute__((ext_vector_type(4))) float f32x4;

#define RSQRT2F 0.70710678118654752440f

__device__ inline void gl_lds16(const void* g, void* l) {
  __builtin_amdgcn_global_load_lds(
      (const __attribute__((address_space(1))) void*)g,
      (__attribute__((address_space(3))) void*)l, 16, 0, 0);
}

// ---- Clifford product tables (verified rounds 0-8) ----
__device__ constexpr int PP_I[64] = {
  0,0,0,0,0,0,0,0,  1,1,1,1,1,1,1,1,  2,2,2,2,2,2,2,2,  3,3,3,3,3,3,3,3,
  4,4,4,4,4,4,4,4,  5,5,5,5,5,5,5,5,  6,6,6,6,6,6,6,6,  7,7,7,7,7,7,7,7};
__device__ constexpr int PP_K[64] = {
  0,1,2,3,4,5,6,7,  0,1,2,3,4,5,6,7,  0,1,2,3,4,5,6,7,  0,1,2,3,4,5,6,7,
  0,1,2,3,4,5,6,7,  0,1,2,3,4,5,6,7,  0,1,2,3,4,5,6,7,  0,1,2,3,4,5,6,7};
__device__ constexpr int PP_C[64] = {
   0, 1, 2, 3, 4, 5, 6, 7,
   9, 8,15,16,13,14,21,20,
  10,15, 8,17,12,21,14,19,
  11,16,17, 8,21,12,13,18,
  29,24,23,35,22,34,33,28,
  30,25,35,23,34,22,32,27,
  31,35,25,24,33,32,22,26,
  43,42,41,40,39,38,37,36};
__device__ constexpr int PP_T[64] = {
   0, 1, 1, 1, 2, 2, 2, 3,
   5, 4, 7, 7, 6, 6, 9, 8,
   5, 7, 4, 7, 6, 9, 6, 8,
   5, 7, 7, 4, 9, 6, 6, 8,
  13,11,11,15,10,14,14,12,
  13,11,15,11,14,10,14,12,
  13,15,11,11,14,14,10,12,
  19,18,18,18,17,17,17,16};
__device__ constexpr int PP_J[64] = {
  0,1,2,3,4,5,6,7,
  1,0,4,5,2,3,7,6,
  2,4,0,6,1,7,3,5,
  3,5,6,0,7,1,2,4,
  4,2,1,7,0,6,5,3,
  5,3,7,1,6,0,4,2,
  6,7,3,2,5,4,0,1,
  7,6,5,4,3,2,1,0};
__device__ constexpr float PP_S[64] = {
  1, 1, 1, 1, 1, 1, 1, 1,
  1, 1, 1, 1, 1, 1, 1, 1,
  1,-1, 1, 1,-1,-1, 1,-1,
  1,-1,-1, 1, 1,-1,-1, 1,
  1,-1, 1, 1,-1,-1, 1,-1,
  1,-1,-1, 1, 1,-1,-1, 1,
  1, 1,-1, 1,-1, 1,-1,-1,
  1, 1,-1, 1,-1, 1,-1,-1};

__device__ constexpr int GJ_CNT[8] = {4,6,6,6,6,6,6,4};
__device__ constexpr int GJ_C[8][6] = {
  {0,8,22,36,0,0},
  {1,9,12,23,26,37},
  {2,10,13,24,27,38},
  {3,11,14,25,28,39},
  {4,15,18,29,32,40},
  {5,16,19,30,33,41},
  {6,17,20,31,34,42},
  {7,21,35,43,0,0}};
__device__ constexpr int GJ_T[8][6] = {
  {0,4,10,16,0,0},
  {1,5,6,11,12,17},
  {1,5,6,11,12,17},
  {1,5,6,11,12,17},
  {2,7,8,13,14,18},
  {2,7,8,13,14,18},
  {2,7,8,13,14,18},
  {3,9,15,19,0,0}};
__device__ constexpr int GRADE[8] = {0,1,1,1,2,2,2,3};

__device__ inline float sigm(float x) { return 1.0f / (1.0f + expf(-x)); }
__device__ inline u16 f2bf(float f) {
  unsigned u = __float_as_uint(f);
  return (u16)((u + 0x7fffu + ((u >> 16) & 1u)) >> 16);
}
__device__ inline float bf2f(u16 h) { return __uint_as_float(((unsigned)h) << 16); }

// ============================================================================
// bf16 MFMA GEMM, multi-pass + split-K over flattened (pass, k-chunk) list.
// blockIdx.z = (set, j, slice). Slices write disjoint partial planes
// [slice*8+j][planeO] (bf16 if out16, else fp32); consumers sum slices.
// 128x128 tile, BK=64, 4 waves, 4x4 frags of 16x16x32 bf16 MFMA.
// Double-buffered global_load_lds staging, s_waitcnt vmcnt(8) so the
// prefetch chunk's DMAs stay in flight across the barrier.
// ============================================================================
#define BT 128
#define MT 128
#define BKc 64

__global__ __launch_bounds__(256) void mfma_gemm(
    const u16* __restrict__ Alin, const u16* __restrict__ Pfeat,
    const u16* __restrict__ WLin, const u16* __restrict__ WLin2,
    const u16* __restrict__ WGp,
    void* __restrict__ out1, void* __restrict__ out2,
    int N, int M, int aug, int planeA, int planeO, int KSbits, int KCbits,
    int out16)
{
  const int zz    = blockIdx.z;
  const int set   = zz >> (3 + KSbits);
  const int rem   = zz & ((8 << KSbits) - 1);
  const int j     = rem >> KSbits;
  const int slice = rem & ((1 << KSbits) - 1);
  const u16* WL   = set ? WLin2 : WLin;
  void* outp      = set ? out2 : out1;

  const int b0   = blockIdx.y * BT;
  const int m0   = blockIdx.x * MT;
  const int tid  = threadIdx.x;
  const int lane = tid & 63;
  const int wave = tid >> 6;
  const int wr   = wave >> 1;
  const int wc   = wave & 1;
  const int l15  = lane & 15;
  const int lq   = lane >> 4;

  __shared__ u16 AsB[2][BT * BKc];
  __shared__ u16 BsB[2][MT * BKc];

  f32x4 zero = {0.f, 0.f, 0.f, 0.f};
  f32x4 acc[4][4];
  #pragma unroll
  for (int r = 0; r < 4; ++r)
    #pragma unroll
    for (int c = 0; c < 4; ++c) acc[r][c] = zero;

  const int g = GRADE[j];
  const int npass = aug ? (1 + GJ_CNT[j]) : 1;
  const int KC = 1 << KCbits;
  const int cper = (npass << KCbits) >> KSbits;   // even division by design
  const int cbeg = slice * cper;

  const int srow  = lane >> 3;   // row within instruction
  const int sslot = lane & 7;    // LDS granule slot

  // prologue: DMA first chunk into buffer 0
  {
    const int ci = cbeg;
    const int p  = ci >> KCbits;
    const int k0 = (ci & (KC - 1)) << 6;
    const u16* Ab = (p == 0) ? Alin + (size_t)j * planeA
                             : Pfeat + (size_t)GJ_C[j][p - 1] * planeA;
    const u16* Wb = (p == 0) ? WL + (size_t)g * M * N
                             : WGp + (size_t)GJ_T[j][p - 1] * (size_t)M * N;
    const u16* As0 = Ab + (size_t)b0 * N + k0;
    const u16* Bs0 = Wb + (size_t)m0 * N + k0;
    #pragma unroll
    for (int q = 0; q < 4; ++q) {
      int inst = wave * 4 + q, row = inst * 8 + srow;
      int kg = sslot ^ (row & 7);
      gl_lds16(As0 + (size_t)row * N + kg * 8, &AsB[0][inst * 512]);
    }
    #pragma unroll
    for (int q = 0; q < 4; ++q) {
      int inst = wave * 4 + q, row = inst * 8 + srow;
      int kg = sslot ^ (row & 7);
      gl_lds16(Bs0 + (size_t)row * N + kg * 8, &BsB[0][inst * 512]);
    }
  }

  #pragma unroll 1
  for (int ci = cbeg; ci < cbeg + cper; ++ci) {
    const int buf = (ci - cbeg) & 1;
    if (ci + 1 < cbeg + cper) {
      const int cn = ci + 1;
      const int p  = cn >> KCbits;
      const int k0 = (cn & (KC - 1)) << 6;
      const u16* Ab = (p == 0) ? Alin + (size_t)j * planeA
                               : Pfeat + (size_t)GJ_C[j][p - 1] * planeA;
      const u16* Wb = (p == 0) ? WL + (size_t)g * M * N
                               : WGp + (size_t)GJ_T[j][p - 1] * (size_t)M * N;
      const u16* As1 = Ab + (size_t)b0 * N + k0;
      const u16* Bs1 = Wb + (size_t)m0 * N + k0;
      #pragma unroll
      for (int q = 0; q < 4; ++q) {
        int inst = wave * 4 + q, row = inst * 8 + srow;
        int kg = sslot ^ (row & 7);
        gl_lds16(As1 + (size_t)row * N + kg * 8, &AsB[1 - buf][inst * 512]);
      }
      #pragma unroll
      for (int q = 0; q < 4; ++q) {
        int inst = wave * 4 + q, row = inst * 8 + srow;
        int kg = sslot ^ (row & 7);
        gl_lds16(Bs1 + (size_t)row * N + kg * 8, &BsB[1 - buf][inst * 512]);
      }
      asm volatile("s_waitcnt vmcnt(8)\n\ts_barrier" ::: "memory");
    } else {
      asm volatile("s_waitcnt vmcnt(0)\n\ts_barrier" ::: "memory");
    }

    const u16* As = &AsB[buf][0];
    const u16* Bs = &BsB[buf][0];
    #pragma unroll
    for (int s = 0; s < 2; ++s) {
      const int kq = s * 4 + lq;
      short8 af[4], bfr[4];
      #pragma unroll
      for (int r = 0; r < 4; ++r) {
        int row = wr * 64 + r * 16 + l15;
        af[r] = *(const short8*)(&As[row * BKc + (kq ^ (row & 7)) * 8]);
      }
      #pragma unroll
      for (int c = 0; c < 4; ++c) {
        int row = wc * 64 + c * 16 + l15;
        bfr[c] = *(const short8*)(&Bs[row * BKc + (kq ^ (row & 7)) * 8]);
      }
      #pragma unroll
      for (int r = 0; r < 4; ++r)
        #pragma unroll
        for (int c = 0; c < 4; ++c)
          acc[r][c] = __builtin_amdgcn_mfma_f32_16x16x32_bf16(af[r], bfr[c], acc[r][c], 0, 0, 0);
    }
    asm volatile("s_barrier" ::: "memory");
  }

  const size_t po = (size_t)(slice * 8 + j) * planeO;
  #pragma unroll
  for (int r = 0; r < 4; ++r)
    #pragma unroll
    for (int c = 0; c < 4; ++c)
      #pragma unroll
      for (int e = 0; e < 4; ++e) {
        int bb = b0 + wr * 64 + r * 16 + lq * 4 + e;
        int mm = m0 + wc * 64 + c * 16 + l15;
        if (out16) ((u16*)outp)[po + (size_t)bb * M + mm] = f2bf(acc[r][c][e]);
        else       ((float*)outp)[po + (size_t)bb * M + mm] = acc[r][c][e];
      }
}

// ============================================================================
// Fused repack (8 weight tensors) + xcast (y==8): fp32 -> bf16 planes
// ============================================================================
struct RepackDesc { const float* in; u16* out; int MN; int S; };
struct RepackArgs { RepackDesc d[8]; const float* x; u16* xp; int PS; };

__global__ void repack_all(RepackArgs a)
{
  int mn = blockIdx.x * 256 + threadIdx.x;
  if (blockIdx.y == 8) {
    if (mn >= a.PS) return;
    float v[8];
    *(float4*)(v)     = *(const float4*)(a.x + (size_t)mn * 8);
    *(float4*)(v + 4) = *(const float4*)(a.x + (size_t)mn * 8 + 4);
    #pragma unroll
    for (int jj = 0; jj < 8; ++jj) a.xp[(size_t)jj * a.PS + mn] = f2bf(v[jj]);
    return;
  }
  RepackDesc d = a.d[blockIdx.y];
  if (mn >= d.MN) return;
  if (d.S == 4) {
    float4 v = ((const float4*)d.in)[mn];
    d.out[(size_t)0 * d.MN + mn] = f2bf(v.x);
    d.out[(size_t)1 * d.MN + mn] = f2bf(v.y);
    d.out[(size_t)2 * d.MN + mn] = f2bf(v.z);
    d.out[(size_t)3 * d.MN + mn] = f2bf(v.w);
  } else {  // S == 20
    #pragma unroll
    for (int q = 0; q < 5; ++q) {
      float4 v = *(const float4*)(d.in + (size_t)mn * 20 + q * 4);
      d.out[(size_t)(q * 4 + 0) * d.MN + mn] = f2bf(v.x);
      d.out[(size_t)(q * 4 + 1) * d.MN + mn] = f2bf(v.y);
      d.out[(size_t)(q * 4 + 2) * d.MN + mn] = f2bf(v.z);
      d.out[(size_t)(q * 4 + 3) * d.MN + mn] = f2bf(v.w);
    }
  }
}

// fused: v = sum of bf16 partial slices -> CGENN norm(na) -> pair products -> P bf16
__global__ void pair_norm_p(const u16* __restrict__ up, const u16* __restrict__ vpart,
                            const float* __restrict__ na, u16* __restrict__ Pp,
                            int PS, int M, int KS)
{
  int t = blockIdx.x * 256 + threadIdx.x;
  if (t >= PS) return;
  int m = t % M;
  float u[8], v[8];
  #pragma unroll
  for (int jj = 0; jj < 8; ++jj) {
    u[jj] = bf2f(up[(size_t)jj * PS + t]);
    float s = 0.f;
    for (int sl = 0; sl < KS; ++sl) s += bf2f(vpart[(size_t)(sl * 8 + jj) * PS + t]);
    v[jj] = s;
  }
  float q[4];
  q[0] = sqrtf(v[0] * v[0]);
  q[1] = sqrtf(v[1] * v[1] + v[2] * v[2] + v[3] * v[3]);
  q[2] = sqrtf(v[4] * v[4] + v[5] * v[5] + v[6] * v[6]);
  q[3] = sqrtf(v[7] * v[7]);
  float sc[4];
  #pragma unroll
  for (int gg = 0; gg < 4; ++gg) {
    float sa = sigm(na[m * 4 + gg]);
    sc[gg] = 1.0f / (sa * (q[gg] - 1.0f) + 1.0f + 1e-6f);
  }
  #pragma unroll
  for (int jj = 0; jj < 8; ++jj) v[jj] *= sc[GRADE[jj]];
  float p[44];
  #pragma unroll
  for (int c = 0; c < 44; ++c) p[c] = 0.f;
  #pragma unroll
  for (int e = 0; e < 64; ++e)
    p[PP_C[e]] += PP_S[e] * u[PP_I[e]] * v[PP_K[e]];
  #pragma unroll
  for (int c = 0; c < 44; ++c) Pp[(size_t)c * PS + t] = f2bf(p[c]);
}

// h = mv_silu((sum of bf16 partial slices + bias0)/sqrt2) -> bf16 planes
__global__ void bias_silu_p(const u16* __restrict__ hpart, const float* __restrict__ bias,
                            const float* __restrict__ ga, const float* __restrict__ gb,
                            u16* __restrict__ sh, int PS, int M, int KS)
{
  int t = blockIdx.x * 256 + threadIdx.x;
  if (t >= PS) return;
  int m = t % M;
  float v[8];
  #pragma unroll
  for (int jj = 0; jj < 8; ++jj) {
    float s = 0.f;
    for (int sl = 0; sl < KS; ++sl) s += bf2f(hpart[(size_t)(sl * 8 + jj) * PS + t]);
    v[jj] = s;
  }
  v[0] += bias[m];
  #pragma unroll
  for (int jj = 0; jj < 8; ++jj) v[jj] *= RSQRT2F;
  float inv[4];
  inv[0] = v[0];
  inv[1] = v[1]*v[1] + v[2]*v[2] + v[3]*v[3];
  inv[2] = v[4]*v[4] + v[5]*v[5] + v[6]*v[6];
  inv[3] = v[7]*v[7];
  float gt[4];
  #pragma unroll
  for (int gg = 0; gg < 4; ++gg)
    gt[gg] = sigm(ga[m * 4 + gg] * inv[gg] + gb[m * 4 + gg]);
  #pragma unroll
  for (int jj = 0; jj < 8; ++jj)
    sh[(size_t)jj * PS + t] = f2bf(v[jj] * gt[GRADE[jj]]);
}

// h2 = mv_silu((llg + bias0 + cwGP(u, norm(hr); wg))/sqrt2); llg/hr bf16 finals
__global__ void cw_silu_p(const u16* __restrict__ llg, const u16* __restrict__ up,
                          const u16* __restrict__ hrraw, const float* __restrict__ na,
                          const float* __restrict__ wg, const float* __restrict__ bias,
                          const float* __restrict__ ga, const float* __restrict__ gb,
                          u16* __restrict__ sh, int PS, int M)
{
  int t = blockIdx.x * 256 + threadIdx.x;
  if (t >= PS) return;
  int n = t % M;
  float acc[8], u[8], v[8], w[20];
  #pragma unroll
  for (int jj = 0; jj < 8; ++jj) {
    acc[jj] = bf2f(llg[(size_t)jj * PS + t]);
    u[jj]   = bf2f(up[(size_t)jj * PS + t]);
    v[jj]   = bf2f(hrraw[(size_t)jj * PS + t]);
  }
  float q[4];
  q[0] = sqrtf(v[0] * v[0]);
  q[1] = sqrtf(v[1] * v[1] + v[2] * v[2] + v[3] * v[3]);
  q[2] = sqrtf(v[4] * v[4] + v[5] * v[5] + v[6] * v[6]);
  q[3] = sqrtf(v[7] * v[7]);
  float sc[4];
  #pragma unroll
  for (int gg = 0; gg < 4; ++gg) {
    float sa = sigm(na[n * 4 + gg]);
    sc[gg] = 1.0f / (sa * (q[gg] - 1.0f) + 1.0f + 1e-6f);
  }
  #pragma unroll
  for (int jj = 0; jj < 8; ++jj) v[jj] *= sc[GRADE[jj]];
  #pragma unroll
  for (int qq = 0; qq < 5; ++qq)
    *(float4*)(w + qq * 4) = *(const float4*)(wg + (size_t)n * 20 + qq * 4);
  acc[0] += bias[n];
  #pragma unroll
  for (int e = 0; e < 64; ++e)
    acc[PP_J[e]] += PP_S[e] * u[PP_I[e]] * v[PP_K[e]] * w[PP_T[e]];
  #pragma unroll
  for (int jj = 0; jj < 8; ++jj) acc[jj] *= RSQRT2F;
  float inv[4];
  inv[0] = acc[0];
  inv[1] = acc[1]*acc[1] + acc[2]*acc[2] + acc[3]*acc[3];
  inv[2] = acc[4]*acc[4] + acc[5]*acc[5] + acc[6]*acc[6];
  inv[3] = acc[7]*acc[7];
  float gt[4];
  #pragma unroll
  for (int gg = 0; gg < 4; ++gg)
    gt[gg] = sigm(ga[n * 4 + gg] * inv[gg] + gb[n * 4 + gg]);
  #pragma unroll
  for (int jj = 0; jj < 8; ++jj)
    sh[(size_t)jj * PS + t] = f2bf(acc[jj] * gt[GRADE[jj]]);
}

// out[b,m,j] = (sum of fp32 partial slices + bias0)/sqrt2, planar -> interleaved
__global__ void final_p(const float* __restrict__ pre, const float* __restrict__ bias,
                        float* __restrict__ outp, int PS, int M, int KS)
{
  int t = blockIdx.x * 256 + threadIdx.x;
  if (t >= PS) return;
  int m = t % M;
  float v[8];
  #pragma unroll
  for (int jj = 0; jj < 8; ++jj) {
    float s = 0.f;
    for (int sl = 0; sl < KS; ++sl) s += pre[(size_t)(sl * 8 + jj) * PS + t];
    v[jj] = s;
  }
  v[0] += bias[m];
  #pragma unroll
  for (int jj = 0; jj < 8; ++jj) v[jj] *= RSQRT2F;
  *(float4*)(outp + (size_t)t * 8)     = *(float4*)(v);
  *(float4*)(outp + (size_t)t * 8 + 4) = *(float4*)(v + 4);
}

// ============================================================================
extern "C" void kernel_launch(void* const* d_in, const int* in_sizes, int n_in,
                              void* d_out, int out_size, void* d_ws, size_t ws_size,
                              hipStream_t stream)
{
  const float* x     = (const float*)d_in[0];
  const float* lr1_w = (const float*)d_in[1];
  const float* n1_a  = (const float*)d_in[2];
  const float* ll1_w = (const float*)d_in[3];
  const float* ll1_b = (const float*)d_in[4];
  const float* w1    = (const float*)d_in[5];
  const float* act_a = (const float*)d_in[6];
  const float* act_b = (const float*)d_in[7];
  const float* lrg_w = (const float*)d_in[8];
  const float* ng_a  = (const float*)d_in[9];
  const float* llg_w = (const float*)d_in[10];
  const float* llg_b = (const float*)d_in[11];
  const float* wg    = (const float*)d_in[12];
  const float* lr2_w = (const float*)d_in[13];
  const float* n2_a  = (const float*)d_in[14];
  const float* ll2_w = (const float*)d_in[15];
  const float* ll2_b = (const float*)d_in[16];
  const float* w2    = (const float*)d_in[17];
  float* out = (float*)d_out;

  // ---- workspace carve-up ----
  u16* W = (u16*)d_ws;
  size_t o = 0;
  u16* WL1  = W + o; o +=  262144;   // [4][256*256]
  u16* WLL1 = W + o; o +=  524288;   // [4][512*256]
  u16* WG1  = W + o; o += 2621440;   // [20][512*256]
  u16* WLRG = W + o; o += 1048576;   // [4][512*512]
  u16* WLLG = W + o; o += 1048576;
  u16* WLR2 = W + o; o += 1048576;
  u16* WLL2 = W + o; o +=  262144;   // [4][128*512]
  u16* WG2  = W + o; o += 1310720;   // [20][128*512]
  u16* XB   = W + o; o += 2097152;   // [8][1024*256]
  u16* HB   = W + o; o += 4194304;   // [8][1024*512] (h1 bf16, then h2 bf16)
  u16* P    = W + o; o += 23068672;  // [44][1024*512]
  u16* PB16 = W + o; o += 8388608;   // bf16 partial arena: 16 planes x PS2 (16MB)
  u16* hr16  = W + o; o += 4194304;  // [8][PS2] bf16
  u16* llg16 = W + o; o += 4194304;  // [8][PS2] bf16
  float* f1 = (float*)(W + o);       // [32][PSO] fp32 ll2 partials (16MB)
  // total ~117 MB < 256 MiB

  dim3 blk(256);
  const int PS1 = 1024 * 256, PS2 = 1024 * 512, PSO = 1024 * 128;

  // ---- fused repacks + xcast ----
  RepackArgs ra = {{
    {lr1_w, WL1, 65536, 4}, {ll1_w, WLL1, 131072, 4}, {w1, WG1, 131072, 20},
    {lrg_w, WLRG, 262144, 4}, {llg_w, WLLG, 262144, 4}, {lr2_w, WLR2, 262144, 4},
    {ll2_w, WLL2, 65536, 4}, {w2, WG2, 65536, 20}},
    x, XB, PS1};
  repack_all<<<dim3(1024, 9), blk, 0, stream>>>(ra);

  // ---- fcgp1 (N=256, M=512) ----
  // lr1: KS=2 -> 256 blocks, bf16 partials
  mfma_gemm<<<dim3(2, 8, 16), blk, 0, stream>>>(XB, nullptr, WL1, nullptr, nullptr,
      PB16, nullptr, 256, 256, 0, PS1, PS1, 1, 2, 1);
  pair_norm_p<<<PS1 / 256, blk, 0, stream>>>(XB, PB16, n1_a, P, PS1, 256, 2);
  // ll1 + w1 aug: KS=2 -> 512 blocks, bf16 partials
  mfma_gemm<<<dim3(4, 8, 16), blk, 0, stream>>>(XB, P, WLL1, nullptr, WG1,
      PB16, nullptr, 256, 512, 1, PS1, PS2, 1, 2, 1);
  bias_silu_p<<<PS2 / 256, blk, 0, stream>>>(PB16, ll1_b, act_a, act_b, HB, PS2, 512, 2);

  // ---- channel-wise GP layer: lrg + llg fused, KS=1 -> 512 blocks, bf16 finals ----
  mfma_gemm<<<dim3(4, 8, 16), blk, 0, stream>>>(HB, nullptr, WLRG, WLLG, nullptr,
      hr16, llg16, 512, 512, 0, PS2, PS2, 0, 3, 1);
  cw_silu_p<<<PS2 / 256, blk, 0, stream>>>(llg16, HB, hr16, ng_a, wg, llg_b, act_a, act_b,
      HB, PS2, 512);

  // ---- fcgp2 (N=512, M=128) ----
  // lr2: KS=2 -> 512 blocks, bf16 partials
  mfma_gemm<<<dim3(4, 8, 16), blk, 0, stream>>>(HB, nullptr, WLR2, nullptr, nullptr,
      PB16, nullptr, 512, 512, 0, PS2, PS2, 1, 3, 1);
  pair_norm_p<<<PS2 / 256, blk, 0, stream>>>(HB, PB16, n2_a, P, PS2, 512, 2);
  // ll2 + w2 aug: KS=4 -> 256 blocks, fp32 partials
  mfma_gemm<<<dim3(1, 8, 32), blk, 0, stream>>>(HB, P, WLL2, nullptr, WG2,
      f1, nullptr, 512, 128, 1, PS2, PSO, 2, 3, 0);
  final_p<<<PSO / 256, blk, 0, stream>>>(f1, ll2_b, out, PSO, 128, 4);
}